// Round 9
// baseline (52.169 us; speedup 1.0000x reference)
//
#include <hip/hip_runtime.h>
#include <hip/hip_bf16.h>
#include <math.h>

#define HWDIM 512
#define HIDDEN 128
#define N_RAYS 524288
#define NUM_CAMS 4096
#define ALPHA 1e-4f

typedef __attribute__((ext_vector_type(4))) float f32x4;
typedef __attribute__((ext_vector_type(8))) short bf16x8;

__device__ __forceinline__ unsigned short f2bf(float f) {
    union { float f; unsigned u; } v; v.f = f;
    unsigned r = v.u + 0x7FFFu + ((v.u >> 16) & 1u);   // RNE
    return (unsigned short)(r >> 16);
}
__device__ __forceinline__ float bf2f(unsigned short s) {
    union { unsigned u; float f; } v; v.u = ((unsigned)s) << 16;
    return v.f;
}

// Software fp8 (s|e4|m3, bias offset 120, FTZ below 2^-6).
__device__ __forceinline__ unsigned f2fp8(float f) {
    unsigned u = __float_as_uint(f);
    u += 0x000FFFFFu + ((u >> 20) & 1u);               // RNE to 3 mantissa bits
    const unsigned s = (u >> 24) & 0x80u;
    const int e = (int)((u >> 23) & 0xFFu) - 120;      // rebias
    const unsigned m = (u >> 20) & 7u;
    return (e <= 0) ? s : (s | ((unsigned)e << 3) | m);
}
__device__ __forceinline__ float fp82f(unsigned b) {
    const unsigned e = (b >> 3) & 0xFu;
    const unsigned u = ((b & 0x80u) << 24) | ((e + 120u) << 23) | ((b & 7u) << 20);
    return (e == 0) ? 0.0f : __uint_as_float(u);
}

// ---------------------------------------------------------------------------
// Kernel 1: plane transpose (C,H,W) f32 -> (plane,H,W,C) fp8.
// Block = (plane, y, 128-px chunk); 4KB LDS tile, XOR-swizzled:
//   read  : wave = 2 x 512B contiguous segments (few long streams)
//   write : wave = 1KB contiguous; consecutive blocks = sequential 4KB
// LDS word layout W(c,pxw) = c*32 + (pxw ^ c): store 2-way (free),
// load 16-bank x 4-lane-broadcast (conflict-free).
// ---------------------------------------------------------------------------
__global__ __launch_bounds__(256) void transpose_kernel(
    const float* __restrict__ pxy,
    const float* __restrict__ pxz,
    const float* __restrict__ pyz,
    unsigned char* __restrict__ tp)      // tp[((p*512+y)*512 + x)*32 + c]
{
    const int blk = blockIdx.x;          // (p*512+y)*4 + xc
    const int xc = blk & 3;
    const int py = blk >> 2;
    const int p = py >> 9;
    const int y = py & (HWDIM - 1);
    const float* plane = (p == 0) ? pxy : ((p == 1) ? pxz : pyz);
    const float* base = plane + (size_t)y * HWDIM + xc * 128;
    const int tid = threadIdx.x;

    __shared__ unsigned int lds[1024];   // 4 KB

    #pragma unroll
    for (int j = 0; j < 4; ++j) {
        const int idx = tid + 256 * j;   // 0..1023
        const int c = idx >> 5;          // channel
        const int f = idx & 31;          // float4 slot (4 px)
        const float4 v = *reinterpret_cast<const float4*>(
            base + (size_t)c * (HWDIM * HWDIM) + f * 4);
        const unsigned w = f2fp8(v.x) | (f2fp8(v.y) << 8)
                         | (f2fp8(v.z) << 16) | (f2fp8(v.w) << 24);
        lds[c * 32 + (f ^ c)] = w;
    }
    __syncthreads();

    // out chunk tid: pixel px = tid>>1, channels c0..c0+15
    const int px = tid >> 1;
    const int c0 = (tid & 1) * 16;
    const int pxw = px >> 2;
    const int bsh = (px & 3) * 8;

    unsigned o[4];
    #pragma unroll
    for (int j = 0; j < 4; ++j) {
        const int cA = c0 + 4 * j;
        const unsigned b0 = (lds[(cA + 0) * 32 + (pxw ^ (cA + 0))] >> bsh) & 0xFFu;
        const unsigned b1 = (lds[(cA + 1) * 32 + (pxw ^ (cA + 1))] >> bsh) & 0xFFu;
        const unsigned b2 = (lds[(cA + 2) * 32 + (pxw ^ (cA + 2))] >> bsh) & 0xFFu;
        const unsigned b3 = (lds[(cA + 3) * 32 + (pxw ^ (cA + 3))] >> bsh) & 0xFFu;
        o[j] = b0 | (b1 << 8) | (b2 << 16) | (b3 << 24);
    }
    *reinterpret_cast<uint4*>(tp + (size_t)blk * 4096 + tid * 16)
        = make_uint4(o[0], o[1], o[2], o[3]);
}

// ---------------------------------------------------------------------------
// Kernel 2: sample from transposed fp8 planes. One thread per
// (cam, plane, ysel, channel-octet): 98304 threads.
// ---------------------------------------------------------------------------
__global__ __launch_bounds__(256) void sample_kernel(
    const float* __restrict__ t,
    const unsigned char* __restrict__ tp,
    float* __restrict__ part)
{
    const int idx = blockIdx.x * 256 + threadIdx.x;   // exactly 98304
    const int co   = idx & 3;
    const int ysel = (idx >> 2) & 1;
    const int pc   = idx >> 3;          // cam*3 + p
    const int p    = pc % 3;
    const int cam  = pc / 3;

    const float ts0 = t[cam * 3 + 0];
    const float ts1 = t[cam * 3 + 1];
    const float ts2 = t[cam * 3 + 2];
    const float cx = (p == 2) ? ts1 : ts0;
    const float cy = (p == 0) ? ts1 : ts2;

    const float x = (cx + 1.0f) * 0.5f * (float)(HWDIM - 1);
    const float y = (cy + 1.0f) * 0.5f * (float)(HWDIM - 1);
    const float x0f = floorf(x);
    const float y0f = floorf(y);
    const float wx = x - x0f;
    const float wy = y - y0f;
    const int x0 = min(max((int)x0f, 0), HWDIM - 1);
    const int x1 = min(max((int)x0f + 1, 0), HWDIM - 1);
    const int y0 = min(max((int)y0f, 0), HWDIM - 1);
    const int y1 = min(max((int)y0f + 1, 0), HWDIM - 1);

    const int yr = ysel ? y1 : y0;
    const float wv = ysel ? wy : (1.0f - wy);

    const unsigned char* rowbase = tp + ((size_t)(p * HWDIM + yr) * HWDIM) * 32;
    const uint2 a0 = *reinterpret_cast<const uint2*>(rowbase + x0 * 32 + co * 8);
    const uint2 a1 = *reinterpret_cast<const uint2*>(rowbase + x1 * 32 + co * 8);

    const unsigned u0[2] = {a0.x, a0.y};
    const unsigned u1[2] = {a1.x, a1.y};
    float r[8];
    #pragma unroll
    for (int wrd = 0; wrd < 2; ++wrd) {
        #pragma unroll
        for (int i = 0; i < 4; ++i) {
            const float v0 = fp82f((u0[wrd] >> (i * 8)) & 0xFFu);
            const float v1 = fp82f((u1[wrd] >> (i * 8)) & 0xFFu);
            r[wrd * 4 + i] = (v0 + (v1 - v0) * wx) * wv;
        }
    }

    float* dst = part + (size_t)cam * 192 + p * 64 + ysel * 32 + co * 8;
    *reinterpret_cast<float4*>(dst)     = make_float4(r[0], r[1], r[2], r[3]);
    *reinterpret_cast<float4*>(dst + 4) = make_float4(r[4], r[5], r[6], r[7]);
}

// ---------------------------------------------------------------------------
// Kernel 3: MFMA MLP (unchanged). 256 blocks; block = 16 cams, 4 waves.
// ---------------------------------------------------------------------------
#define W1S 104   // 96 + 8 pad (shorts)
#define W2S 136   // 128 + 8 pad
#define HS  136

__global__ __launch_bounds__(256) void mlp_kernel(
    const float* __restrict__ part,
    const float* __restrict__ t,
    const float* __restrict__ w1, const float* __restrict__ b1,
    const float* __restrict__ w2, const float* __restrict__ b2,
    const float* __restrict__ w3, const float* __restrict__ b3,
    const float* __restrict__ init_c2w,
    float* __restrict__ table)
{
    const int tid  = threadIdx.x;
    const int lane = tid & 63;
    const int wave = tid >> 6;
    const int cam0 = blockIdx.x * 16;
    const int ncol = lane & 15;
    const int kgrp = lane >> 4;

    __shared__ unsigned short w1t[128][W1S];
    __shared__ unsigned short w2t[128][W2S];
    __shared__ unsigned short h0t[16][W1S];
    __shared__ unsigned short h1t[16][HS];
    __shared__ unsigned short h2t[16][HS];
    __shared__ float b1s[128], b2s[128], w3s[384];
    __shared__ float rotc[16][3];
    __shared__ float c2ws[16][12];

    {
        const float4* w1v = (const float4*)w1;
        for (int i = tid; i < (96 * 128) / 4; i += 256) {
            const float4 v = w1v[i];
            const int flat = i * 4;
            const int k = flat >> 7, n = flat & 127;
            w1t[n + 0][k] = f2bf(v.x);
            w1t[n + 1][k] = f2bf(v.y);
            w1t[n + 2][k] = f2bf(v.z);
            w1t[n + 3][k] = f2bf(v.w);
        }
        const float4* w2v = (const float4*)w2;
        for (int i = tid; i < (128 * 128) / 4; i += 256) {
            const float4 v = w2v[i];
            const int flat = i * 4;
            const int k = flat >> 7, n = flat & 127;
            w2t[n + 0][k] = f2bf(v.x);
            w2t[n + 1][k] = f2bf(v.y);
            w2t[n + 2][k] = f2bf(v.z);
            w2t[n + 3][k] = f2bf(v.w);
        }
    }
    // assemble layer-1 input: codes = part[...,ysel=0] + part[...,ysel=1]
    #pragma unroll
    for (int j = 0; j < 6; ++j) {
        const int idx = tid + 256 * j;           // 16*96 = 1536 tasks
        const int cl = idx / 96;
        const int f = idx - cl * 96;
        const size_t base = (size_t)(cam0 + cl) * 192 + (f >> 5) * 64 + (f & 31);
        h0t[cl][f] = f2bf(part[base] + part[base + 32]);
    }
    if (tid < 128) { b1s[tid] = b1[tid]; b2s[tid] = b2[tid]; }
    for (int i = tid; i < 384; i += 256) w3s[i] = w3[i];
    __syncthreads();

    const int nb0 = wave * 32 + ncol;
    const int nb1 = nb0 + 16;

    f32x4 acc0, acc1;
    {
        const float bv0 = b1s[nb0], bv1 = b1s[nb1];
        acc0 = (f32x4){bv0, bv0, bv0, bv0};
        acc1 = (f32x4){bv1, bv1, bv1, bv1};
    }
    #pragma unroll
    for (int k0 = 0; k0 < 96; k0 += 32) {
        const bf16x8 a   = *reinterpret_cast<const bf16x8*>(&h0t[ncol][k0 + kgrp * 8]);
        const bf16x8 bb0 = *reinterpret_cast<const bf16x8*>(&w1t[nb0][k0 + kgrp * 8]);
        const bf16x8 bb1 = *reinterpret_cast<const bf16x8*>(&w1t[nb1][k0 + kgrp * 8]);
        acc0 = __builtin_amdgcn_mfma_f32_16x16x32_bf16(a, bb0, acc0, 0, 0, 0);
        acc1 = __builtin_amdgcn_mfma_f32_16x16x32_bf16(a, bb1, acc1, 0, 0, 0);
    }
    #pragma unroll
    for (int r = 0; r < 4; ++r) {
        const int camr = kgrp * 4 + r;
        const float v0 = acc0[r];
        const float v1 = acc1[r];
        h1t[camr][nb0] = f2bf(v0 / (1.0f + __expf(-v0)));
        h1t[camr][nb1] = f2bf(v1 / (1.0f + __expf(-v1)));
    }
    __syncthreads();

    {
        const float bv0 = b2s[nb0], bv1 = b2s[nb1];
        acc0 = (f32x4){bv0, bv0, bv0, bv0};
        acc1 = (f32x4){bv1, bv1, bv1, bv1};
    }
    #pragma unroll
    for (int k0 = 0; k0 < 128; k0 += 32) {
        const bf16x8 a   = *reinterpret_cast<const bf16x8*>(&h1t[ncol][k0 + kgrp * 8]);
        const bf16x8 bb0 = *reinterpret_cast<const bf16x8*>(&w2t[nb0][k0 + kgrp * 8]);
        const bf16x8 bb1 = *reinterpret_cast<const bf16x8*>(&w2t[nb1][k0 + kgrp * 8]);
        acc0 = __builtin_amdgcn_mfma_f32_16x16x32_bf16(a, bb0, acc0, 0, 0, 0);
        acc1 = __builtin_amdgcn_mfma_f32_16x16x32_bf16(a, bb1, acc1, 0, 0, 0);
    }
    #pragma unroll
    for (int r = 0; r < 4; ++r) {
        const int camr = kgrp * 4 + r;
        const float v0 = acc0[r];
        const float v1 = acc1[r];
        h2t[camr][nb0] = f2bf(v0 / (1.0f + __expf(-v0)));
        h2t[camr][nb1] = f2bf(v1 / (1.0f + __expf(-v1)));
    }
    __syncthreads();

    if (tid < 64) {
        const int cam = tid >> 2, c = tid & 3;
        if (c < 3) {
            float acc = b3[c];
            for (int k = 0; k < 128; ++k)
                acc += bf2f(h2t[cam][k]) * w3s[k * 3 + c];
            rotc[cam][c] = acc * ALPHA;
        }
    }
    __syncthreads();

    if (tid < 16) {
        const int cam = tid;
        const float a = rotc[cam][0], b = rotc[cam][1], c = rotc[cam][2];
        const float th2 = a * a + b * b + c * c;
        const float th = sqrtf(th2);
        const float A = sinf(th) / (th + 1e-10f);
        const float B = (1.0f - cosf(th)) / (th2 + 1e-10f);
        const float ts0 = t[(cam0 + cam) * 3 + 0];
        const float ts1 = t[(cam0 + cam) * 3 + 1];
        const float ts2 = t[(cam0 + cam) * 3 + 2];
        c2ws[cam][0]  = 1.0f + B * (-(c * c + b * b));
        c2ws[cam][1]  = A * (-c) + B * (a * b);
        c2ws[cam][2]  = A * b + B * (a * c);
        c2ws[cam][3]  = ts0;
        c2ws[cam][4]  = A * c + B * (a * b);
        c2ws[cam][5]  = 1.0f + B * (-(c * c + a * a));
        c2ws[cam][6]  = A * (-a) + B * (b * c);
        c2ws[cam][7]  = ts1;
        c2ws[cam][8]  = A * (-b) + B * (a * c);
        c2ws[cam][9]  = A * a + B * (b * c);
        c2ws[cam][10] = 1.0f + B * (-(a * a + b * b));
        c2ws[cam][11] = ts2;
    }
    __syncthreads();

    {
        const int cam = tid >> 4, e = tid & 15, i = e >> 2, j = e & 3;
        const float* ic = init_c2w + (size_t)(cam0 + cam) * 16;
        float v;
        if (i < 3) {
            const float* cw = c2ws[cam];
            v = cw[i * 4 + 0] * ic[0 + j]
              + cw[i * 4 + 1] * ic[4 + j]
              + cw[i * 4 + 2] * ic[8 + j]
              + cw[i * 4 + 3] * ic[12 + j];
        } else {
            v = ic[12 + j];
        }
        table[(size_t)cam0 * 16 + tid] = v;
    }
}

// ---------------------------------------------------------------------------
// Kernel 4: gather per-camera 4x4 into per-ray output (float4 per thread).
// ---------------------------------------------------------------------------
__global__ __launch_bounds__(256) void gather_kernel(
    const int* __restrict__ cam_id,
    const float4* __restrict__ table,
    float4* __restrict__ out)
{
    const int idx = blockIdx.x * blockDim.x + threadIdx.x;
    if (idx >= N_RAYS * 4) return;
    const int ray = idx >> 2;
    const int q = idx & 3;
    const int cid = cam_id[ray];
    out[idx] = table[cid * 4 + q];
}

extern "C" void kernel_launch(void* const* d_in, const int* in_sizes, int n_in,
                              void* d_out, int out_size, void* d_ws, size_t ws_size,
                              hipStream_t stream) {
    const int*   cam_id   = (const int*)  d_in[0];
    const float* t        = (const float*)d_in[1];
    const float* pxy      = (const float*)d_in[2];
    const float* pxz      = (const float*)d_in[3];
    const float* pyz      = (const float*)d_in[4];
    const float* w1       = (const float*)d_in[5];
    const float* b1       = (const float*)d_in[6];
    const float* w2       = (const float*)d_in[7];
    const float* b2       = (const float*)d_in[8];
    const float* w3       = (const float*)d_in[9];
    const float* b3       = (const float*)d_in[10];
    const float* init_c2w = (const float*)d_in[11];

    // ws layout (bytes):
    // [0, 256K)                      table : 4096 x 16 f32
    // [256K, 256K+3M)                part  : 4096 x 3 x 2 x 32 f32
    // [3407872, 3407872+24M)         tp    : 3 x 512 x 512 x 32 fp8
    char* ws = (char*)d_ws;
    float* table = (float*)ws;
    float* part  = (float*)(ws + 262144);
    unsigned char* tp = (unsigned char*)(ws + 3407872);

    transpose_kernel<<<3 * HWDIM * 4, 256, 0, stream>>>(pxy, pxz, pyz, tp);
    sample_kernel<<<(NUM_CAMS * 24) / 256, 256, 0, stream>>>(t, tp, part);
    mlp_kernel<<<NUM_CAMS / 16, 256, 0, stream>>>(
        part, t, w1, b1, w2, b2, w3, b3, init_c2w, table);
    const int total = N_RAYS * 4;
    gather_kernel<<<(total + 255) / 256, 256, 0, stream>>>(
        cam_id, (const float4*)table, (float4*)d_out);
}

// Round 10
// 38.903 us; speedup vs baseline: 1.3410x; 1.3410x over previous
//
#include <hip/hip_runtime.h>
#include <hip/hip_bf16.h>
#include <math.h>

#define HWDIM 512
#define HIDDEN 128
#define N_RAYS 524288
#define NUM_CAMS 4096
#define ALPHA 1e-4f

typedef __attribute__((ext_vector_type(4))) float f32x4;
typedef __attribute__((ext_vector_type(8))) short bf16x8;

__device__ __forceinline__ unsigned short f2bf(float f) {
    union { float f; unsigned u; } v; v.f = f;
    unsigned r = v.u + 0x7FFFu + ((v.u >> 16) & 1u);   // RNE
    return (unsigned short)(r >> 16);
}
__device__ __forceinline__ float bf2f(unsigned short s) {
    union { unsigned u; float f; } v; v.u = ((unsigned)s) << 16;
    return v.f;
}

// ---------------------------------------------------------------------------
// Kernel 0: weight prep. w1 (96x128 f32, k-major) -> w1T (128x96 bf16,
// n-major); w2 likewise. 57KB total, L2-resident for the fused kernel.
// ---------------------------------------------------------------------------
__global__ __launch_bounds__(256) void prep_kernel(
    const float* __restrict__ w1, const float* __restrict__ w2,
    unsigned short* __restrict__ w1T, unsigned short* __restrict__ w2T)
{
    const int idx = blockIdx.x * 256 + threadIdx.x;    // 28672 exactly
    if (idx < 96 * 128) {
        const int k = idx >> 7, n = idx & 127;         // coalesced read
        w1T[n * 96 + k] = f2bf(w1[idx]);
    } else {
        const int j = idx - 96 * 128;
        const int k = j >> 7, n = j & 127;
        w2T[n * 128 + k] = f2bf(w2[j]);
    }
}

// ---------------------------------------------------------------------------
// Kernel 1: FUSED sample + MLP + Rodrigues + compose. Block = 16 cams,
// 512 threads (8 waves). Phase A: 1536 bilinear taps (3/thread, 12 scattered
// loads) -> h0 bf16 in LDS. Phase B/C: MFMA layers, B-fragments loaded
// directly from L2-resident w1T/w2T (no LDS weight staging -> small LDS).
// Phase D: layer3 + Rodrigues + c2w @ init_c2w -> table.
// ---------------------------------------------------------------------------
__global__ __launch_bounds__(512) void fused_kernel(
    const float* __restrict__ t,
    const float* __restrict__ pxy,
    const float* __restrict__ pxz,
    const float* __restrict__ pyz,
    const unsigned short* __restrict__ w1T, const float* __restrict__ b1,
    const unsigned short* __restrict__ w2T, const float* __restrict__ b2,
    const float* __restrict__ w3, const float* __restrict__ b3,
    const float* __restrict__ init_c2w,
    float* __restrict__ table)
{
    const int tid  = threadIdx.x;
    const int lane = tid & 63;
    const int wave = tid >> 6;          // 0..7
    const int cam0 = blockIdx.x * 16;
    const int ncol = lane & 15;
    const int kgrp = lane >> 4;

    __shared__ unsigned short h0t[16][104];   // 96 + 8 pad
    __shared__ unsigned short h1t[16][136];   // 128 + 8 pad
    __shared__ unsigned short h2t[16][136];
    __shared__ float w3s[384];
    __shared__ float rotc[16][3];
    __shared__ float c2ws[16][12];

    // --- phase A: 16 cams x 96 features, 3 tasks/thread, 12 scattered loads ---
    #pragma unroll
    for (int j = 0; j < 3; ++j) {
        const int task = tid + 512 * j;      // 0..1535
        const int cl = task / 96;
        const int f = task - cl * 96;
        const int p = f >> 5;
        const int c = f & 31;
        const int cam = cam0 + cl;

        const float ts0 = t[cam * 3 + 0];
        const float ts1 = t[cam * 3 + 1];
        const float ts2 = t[cam * 3 + 2];
        const float cx = (p == 2) ? ts1 : ts0;
        const float cy = (p == 0) ? ts1 : ts2;
        const float* plane = (p == 0) ? pxy : ((p == 1) ? pxz : pyz);

        const float x = (cx + 1.0f) * 0.5f * (float)(HWDIM - 1);
        const float y = (cy + 1.0f) * 0.5f * (float)(HWDIM - 1);
        const float x0f = floorf(x);
        const float y0f = floorf(y);
        const float wx = x - x0f;
        const float wy = y - y0f;
        const int x0 = min(max((int)x0f, 0), HWDIM - 1);
        const int x1 = min(max((int)x0f + 1, 0), HWDIM - 1);
        const int y0 = min(max((int)y0f, 0), HWDIM - 1);
        const int y1 = min(max((int)y0f + 1, 0), HWDIM - 1);

        const float* pc = plane + (size_t)c * (HWDIM * HWDIM);
        const float v00 = pc[y0 * HWDIM + x0];
        const float v01 = pc[y0 * HWDIM + x1];
        const float v10 = pc[y1 * HWDIM + x0];
        const float v11 = pc[y1 * HWDIM + x1];

        const float val = v00 * (1.0f - wx) * (1.0f - wy)
                        + v01 * wx          * (1.0f - wy)
                        + v10 * (1.0f - wx) * wy
                        + v11 * wx          * wy;
        h0t[cl][f] = f2bf(val);
    }
    if (tid < 384) w3s[tid] = w3[tid];
    __syncthreads();

    // --- layer 1: h0(16x96) @ w1 + b1, silu. wave owns 16 output cols ---
    const int nb = wave * 16 + ncol;     // 0..127
    f32x4 acc;
    { const float bv = b1[nb]; acc = (f32x4){bv, bv, bv, bv}; }
    #pragma unroll
    for (int k0 = 0; k0 < 96; k0 += 32) {
        const bf16x8 a  = *reinterpret_cast<const bf16x8*>(&h0t[ncol][k0 + kgrp * 8]);
        const bf16x8 bb = *reinterpret_cast<const bf16x8*>(w1T + nb * 96 + k0 + kgrp * 8);
        acc = __builtin_amdgcn_mfma_f32_16x16x32_bf16(a, bb, acc, 0, 0, 0);
    }
    #pragma unroll
    for (int r = 0; r < 4; ++r) {
        const int camr = kgrp * 4 + r;
        const float v = acc[r];
        h1t[camr][nb] = f2bf(v / (1.0f + __expf(-v)));
    }
    __syncthreads();

    // --- layer 2: h1(16x128) @ w2 + b2, silu ---
    { const float bv = b2[nb]; acc = (f32x4){bv, bv, bv, bv}; }
    #pragma unroll
    for (int k0 = 0; k0 < 128; k0 += 32) {
        const bf16x8 a  = *reinterpret_cast<const bf16x8*>(&h1t[ncol][k0 + kgrp * 8]);
        const bf16x8 bb = *reinterpret_cast<const bf16x8*>(w2T + nb * 128 + k0 + kgrp * 8);
        acc = __builtin_amdgcn_mfma_f32_16x16x32_bf16(a, bb, acc, 0, 0, 0);
    }
    #pragma unroll
    for (int r = 0; r < 4; ++r) {
        const int camr = kgrp * 4 + r;
        const float v = acc[r];
        h2t[camr][nb] = f2bf(v / (1.0f + __expf(-v)));
    }
    __syncthreads();

    // --- layer 3: h2(16x128) @ w3(128x3) + b3, * ALPHA ---
    if (tid < 64) {
        const int cam = tid >> 2, c = tid & 3;
        if (c < 3) {
            float a3 = b3[c];
            for (int k = 0; k < 128; ++k)
                a3 += bf2f(h2t[cam][k]) * w3s[k * 3 + c];
            rotc[cam][c] = a3 * ALPHA;
        }
    }
    __syncthreads();

    // --- Rodrigues + [R|ts] ---
    if (tid < 16) {
        const int cam = tid;
        const float a = rotc[cam][0], b = rotc[cam][1], c = rotc[cam][2];
        const float th2 = a * a + b * b + c * c;
        const float th = sqrtf(th2);
        const float A = sinf(th) / (th + 1e-10f);
        const float B = (1.0f - cosf(th)) / (th2 + 1e-10f);
        const float ts0 = t[(cam0 + cam) * 3 + 0];
        const float ts1 = t[(cam0 + cam) * 3 + 1];
        const float ts2 = t[(cam0 + cam) * 3 + 2];
        c2ws[cam][0]  = 1.0f + B * (-(c * c + b * b));
        c2ws[cam][1]  = A * (-c) + B * (a * b);
        c2ws[cam][2]  = A * b + B * (a * c);
        c2ws[cam][3]  = ts0;
        c2ws[cam][4]  = A * c + B * (a * b);
        c2ws[cam][5]  = 1.0f + B * (-(c * c + a * a));
        c2ws[cam][6]  = A * (-a) + B * (b * c);
        c2ws[cam][7]  = ts1;
        c2ws[cam][8]  = A * (-b) + B * (a * c);
        c2ws[cam][9]  = A * a + B * (b * c);
        c2ws[cam][10] = 1.0f + B * (-(a * a + b * b));
        c2ws[cam][11] = ts2;
    }
    __syncthreads();

    // --- out = c2w @ init_c2w[cam]; threads 0..255, 16 per cam ---
    if (tid < 256) {
        const int cam = tid >> 4, e = tid & 15, i = e >> 2, j = e & 3;
        const float* ic = init_c2w + (size_t)(cam0 + cam) * 16;
        float v;
        if (i < 3) {
            const float* cw = c2ws[cam];
            v = cw[i * 4 + 0] * ic[0 + j]
              + cw[i * 4 + 1] * ic[4 + j]
              + cw[i * 4 + 2] * ic[8 + j]
              + cw[i * 4 + 3] * ic[12 + j];
        } else {
            v = ic[12 + j];
        }
        table[(size_t)cam0 * 16 + tid] = v;
    }
}

// ---------------------------------------------------------------------------
// Kernel 2: gather per-camera 4x4 into per-ray output (float4 per thread).
// ---------------------------------------------------------------------------
__global__ __launch_bounds__(256) void gather_kernel(
    const int* __restrict__ cam_id,
    const float4* __restrict__ table,
    float4* __restrict__ out)
{
    const int idx = blockIdx.x * blockDim.x + threadIdx.x;
    if (idx >= N_RAYS * 4) return;
    const int ray = idx >> 2;
    const int q = idx & 3;
    const int cid = cam_id[ray];
    out[idx] = table[cid * 4 + q];
}

extern "C" void kernel_launch(void* const* d_in, const int* in_sizes, int n_in,
                              void* d_out, int out_size, void* d_ws, size_t ws_size,
                              hipStream_t stream) {
    const int*   cam_id   = (const int*)  d_in[0];
    const float* t        = (const float*)d_in[1];
    const float* pxy      = (const float*)d_in[2];
    const float* pxz      = (const float*)d_in[3];
    const float* pyz      = (const float*)d_in[4];
    const float* w1       = (const float*)d_in[5];
    const float* b1       = (const float*)d_in[6];
    const float* w2       = (const float*)d_in[7];
    const float* b2       = (const float*)d_in[8];
    const float* w3       = (const float*)d_in[9];
    const float* b3       = (const float*)d_in[10];
    const float* init_c2w = (const float*)d_in[11];

    // ws layout (bytes):
    // [0, 256K)           table : 4096 x 16 f32
    // [256K, +24576)      w1T   : 128 x 96 bf16
    // [.., +32768)        w2T   : 128 x 128 bf16
    char* ws = (char*)d_ws;
    float* table = (float*)ws;
    unsigned short* w1T = (unsigned short*)(ws + 262144);
    unsigned short* w2T = (unsigned short*)(ws + 262144 + 24576);

    prep_kernel<<<112, 256, 0, stream>>>(w1, w2, w1T, w2T);
    fused_kernel<<<NUM_CAMS / 16, 512, 0, stream>>>(
        t, pxy, pxz, pyz, w1T, b1, w2T, b2, w3, b3, init_c2w, table);
    const int total = N_RAYS * 4;
    gather_kernel<<<(total + 255) / 256, 256, 0, stream>>>(
        cam_id, (const float4*)table, (float4*)d_out);
}

// Round 11
// 38.495 us; speedup vs baseline: 1.3552x; 1.0106x over previous
//
#include <hip/hip_runtime.h>
#include <hip/hip_bf16.h>
#include <math.h>

#define HWDIM 512
#define HIDDEN 128
#define N_RAYS 524288
#define NUM_CAMS 4096
#define ALPHA 1e-4f

typedef __attribute__((ext_vector_type(4))) float f32x4;
typedef __attribute__((ext_vector_type(8))) short bf16x8;

__device__ __forceinline__ unsigned short f2bf(float f) {
    union { float f; unsigned u; } v; v.f = f;
    unsigned r = v.u + 0x7FFFu + ((v.u >> 16) & 1u);   // RNE
    return (unsigned short)(r >> 16);
}
__device__ __forceinline__ float bf2f(unsigned short s) {
    union { unsigned u; float f; } v; v.u = ((unsigned)s) << 16;
    return v.f;
}

// ---------------------------------------------------------------------------
// Kernel 0: weight prep. w1 (96x128 f32, k-major) -> w1T (128x96 bf16,
// n-major); w2 likewise. 57KB total, L2-resident for the fused kernel.
// ---------------------------------------------------------------------------
__global__ __launch_bounds__(256) void prep_kernel(
    const float* __restrict__ w1, const float* __restrict__ w2,
    unsigned short* __restrict__ w1T, unsigned short* __restrict__ w2T)
{
    const int idx = blockIdx.x * 256 + threadIdx.x;    // 28672 exactly
    if (idx < 96 * 128) {
        const int k = idx >> 7, n = idx & 127;         // coalesced read
        w1T[n * 96 + k] = f2bf(w1[idx]);
    } else {
        const int j = idx - 96 * 128;
        const int k = j >> 7, n = j & 127;
        w2T[n * 128 + k] = f2bf(w2[j]);
    }
}

// ---------------------------------------------------------------------------
// Kernel 1: FUSED sample + MLP + Rodrigues + compose. Block = 16 cams,
// 512 threads (8 waves). Phase A: t preloaded to LDS; all 12 scattered tap
// loads issued back-to-back (addr[]/val[] split) before interpolation.
// Phase B/C: MFMA layers, B-fragments from L2-resident w1T/w2T.
// Phase D: layer3 + Rodrigues + c2w @ init_c2w -> table.
// ---------------------------------------------------------------------------
__global__ __launch_bounds__(512) void fused_kernel(
    const float* __restrict__ t,
    const float* __restrict__ pxy,
    const float* __restrict__ pxz,
    const float* __restrict__ pyz,
    const unsigned short* __restrict__ w1T, const float* __restrict__ b1,
    const unsigned short* __restrict__ w2T, const float* __restrict__ b2,
    const float* __restrict__ w3, const float* __restrict__ b3,
    const float* __restrict__ init_c2w,
    float* __restrict__ table)
{
    const int tid  = threadIdx.x;
    const int lane = tid & 63;
    const int wave = tid >> 6;          // 0..7
    const int cam0 = blockIdx.x * 16;
    const int ncol = lane & 15;
    const int kgrp = lane >> 4;

    __shared__ float tvals[48];               // 16 cams x 3
    __shared__ unsigned short h0t[16][104];   // 96 + 8 pad
    __shared__ unsigned short h1t[16][136];   // 128 + 8 pad
    __shared__ unsigned short h2t[16][136];
    __shared__ float w3s[384];
    __shared__ float rotc[16][3];
    __shared__ float c2ws[16][12];

    if (tid < 48) tvals[tid] = t[cam0 * 3 + tid];
    if (tid < 384) w3s[tid] = w3[tid];
    __syncthreads();

    // --- phase A: 1536 tap tasks, 3/thread. Compute all addresses, issue
    // all 12 loads, then interpolate (single miss epoch). ---
    const float* tapptr[3][4];
    float wxa[3], wya[3];
    int cla[3], fa[3];
    #pragma unroll
    for (int j = 0; j < 3; ++j) {
        const int task = tid + 512 * j;      // 0..1535
        const int cl = task / 96;
        const int f = task - cl * 96;
        const int p = f >> 5;
        const int c = f & 31;
        cla[j] = cl; fa[j] = f;

        const float cx = (p == 2) ? tvals[cl * 3 + 1] : tvals[cl * 3 + 0];
        const float cy = (p == 0) ? tvals[cl * 3 + 1] : tvals[cl * 3 + 2];
        const float* plane = (p == 0) ? pxy : ((p == 1) ? pxz : pyz);

        const float x = (cx + 1.0f) * 0.5f * (float)(HWDIM - 1);
        const float y = (cy + 1.0f) * 0.5f * (float)(HWDIM - 1);
        const float x0f = floorf(x);
        const float y0f = floorf(y);
        wxa[j] = x - x0f;
        wya[j] = y - y0f;
        const int x0 = min(max((int)x0f, 0), HWDIM - 1);
        const int x1 = min(max((int)x0f + 1, 0), HWDIM - 1);
        const int y0 = min(max((int)y0f, 0), HWDIM - 1);
        const int y1 = min(max((int)y0f + 1, 0), HWDIM - 1);

        const float* pc = plane + (size_t)c * (HWDIM * HWDIM);
        tapptr[j][0] = pc + y0 * HWDIM + x0;
        tapptr[j][1] = pc + y0 * HWDIM + x1;
        tapptr[j][2] = pc + y1 * HWDIM + x0;
        tapptr[j][3] = pc + y1 * HWDIM + x1;
    }
    float tv[3][4];
    #pragma unroll
    for (int j = 0; j < 3; ++j)
        #pragma unroll
        for (int k = 0; k < 4; ++k)
            tv[j][k] = *tapptr[j][k];
    #pragma unroll
    for (int j = 0; j < 3; ++j) {
        const float wx = wxa[j], wy = wya[j];
        const float val = tv[j][0] * (1.0f - wx) * (1.0f - wy)
                        + tv[j][1] * wx          * (1.0f - wy)
                        + tv[j][2] * (1.0f - wx) * wy
                        + tv[j][3] * wx          * wy;
        h0t[cla[j]][fa[j]] = f2bf(val);
    }
    __syncthreads();

    // --- layer 1: h0(16x96) @ w1 + b1, silu. wave owns 16 output cols ---
    const int nb = wave * 16 + ncol;     // 0..127
    f32x4 acc;
    { const float bv = b1[nb]; acc = (f32x4){bv, bv, bv, bv}; }
    #pragma unroll
    for (int k0 = 0; k0 < 96; k0 += 32) {
        const bf16x8 a  = *reinterpret_cast<const bf16x8*>(&h0t[ncol][k0 + kgrp * 8]);
        const bf16x8 bb = *reinterpret_cast<const bf16x8*>(w1T + nb * 96 + k0 + kgrp * 8);
        acc = __builtin_amdgcn_mfma_f32_16x16x32_bf16(a, bb, acc, 0, 0, 0);
    }
    #pragma unroll
    for (int r = 0; r < 4; ++r) {
        const int camr = kgrp * 4 + r;
        const float v = acc[r];
        h1t[camr][nb] = f2bf(v / (1.0f + __expf(-v)));
    }
    __syncthreads();

    // --- layer 2: h1(16x128) @ w2 + b2, silu ---
    { const float bv = b2[nb]; acc = (f32x4){bv, bv, bv, bv}; }
    #pragma unroll
    for (int k0 = 0; k0 < 128; k0 += 32) {
        const bf16x8 a  = *reinterpret_cast<const bf16x8*>(&h1t[ncol][k0 + kgrp * 8]);
        const bf16x8 bb = *reinterpret_cast<const bf16x8*>(w2T + nb * 128 + k0 + kgrp * 8);
        acc = __builtin_amdgcn_mfma_f32_16x16x32_bf16(a, bb, acc, 0, 0, 0);
    }
    #pragma unroll
    for (int r = 0; r < 4; ++r) {
        const int camr = kgrp * 4 + r;
        const float v = acc[r];
        h2t[camr][nb] = f2bf(v / (1.0f + __expf(-v)));
    }
    __syncthreads();

    // --- layer 3: h2(16x128) @ w3(128x3) + b3, * ALPHA ---
    if (tid < 64) {
        const int cam = tid >> 2, c = tid & 3;
        if (c < 3) {
            float a3 = b3[c];
            for (int k = 0; k < 128; ++k)
                a3 += bf2f(h2t[cam][k]) * w3s[k * 3 + c];
            rotc[cam][c] = a3 * ALPHA;
        }
    }
    __syncthreads();

    // --- Rodrigues + [R|ts] ---
    if (tid < 16) {
        const int cam = tid;
        const float a = rotc[cam][0], b = rotc[cam][1], c = rotc[cam][2];
        const float th2 = a * a + b * b + c * c;
        const float th = sqrtf(th2);
        const float A = sinf(th) / (th + 1e-10f);
        const float B = (1.0f - cosf(th)) / (th2 + 1e-10f);
        const float ts0 = tvals[cam * 3 + 0];
        const float ts1 = tvals[cam * 3 + 1];
        const float ts2 = tvals[cam * 3 + 2];
        c2ws[cam][0]  = 1.0f + B * (-(c * c + b * b));
        c2ws[cam][1]  = A * (-c) + B * (a * b);
        c2ws[cam][2]  = A * b + B * (a * c);
        c2ws[cam][3]  = ts0;
        c2ws[cam][4]  = A * c + B * (a * b);
        c2ws[cam][5]  = 1.0f + B * (-(c * c + a * a));
        c2ws[cam][6]  = A * (-a) + B * (b * c);
        c2ws[cam][7]  = ts1;
        c2ws[cam][8]  = A * (-b) + B * (a * c);
        c2ws[cam][9]  = A * a + B * (b * c);
        c2ws[cam][10] = 1.0f + B * (-(a * a + b * b));
        c2ws[cam][11] = ts2;
    }
    __syncthreads();

    // --- out = c2w @ init_c2w[cam]; threads 0..255, 16 per cam ---
    if (tid < 256) {
        const int cam = tid >> 4, e = tid & 15, i = e >> 2, j = e & 3;
        const float* ic = init_c2w + (size_t)(cam0 + cam) * 16;
        float v;
        if (i < 3) {
            const float* cw = c2ws[cam];
            v = cw[i * 4 + 0] * ic[0 + j]
              + cw[i * 4 + 1] * ic[4 + j]
              + cw[i * 4 + 2] * ic[8 + j]
              + cw[i * 4 + 3] * ic[12 + j];
        } else {
            v = ic[12 + j];
        }
        table[(size_t)cam0 * 16 + tid] = v;
    }
}

// ---------------------------------------------------------------------------
// Kernel 2: gather. Grid-stride, 2048 blocks; thread writes one float4
// quarter-row per iteration (fully coalesced).
// ---------------------------------------------------------------------------
__global__ __launch_bounds__(256) void gather_kernel(
    const int* __restrict__ cam_id,
    const float4* __restrict__ table,
    float4* __restrict__ out)
{
    const int total = N_RAYS * 4;
    const int stride = 2048 * 256;
    for (int idx = blockIdx.x * 256 + threadIdx.x; idx < total; idx += stride) {
        const int ray = idx >> 2;
        const int q = idx & 3;
        const int cid = cam_id[ray];
        out[idx] = table[cid * 4 + q];
    }
}

extern "C" void kernel_launch(void* const* d_in, const int* in_sizes, int n_in,
                              void* d_out, int out_size, void* d_ws, size_t ws_size,
                              hipStream_t stream) {
    const int*   cam_id   = (const int*)  d_in[0];
    const float* t        = (const float*)d_in[1];
    const float* pxy      = (const float*)d_in[2];
    const float* pxz      = (const float*)d_in[3];
    const float* pyz      = (const float*)d_in[4];
    const float* w1       = (const float*)d_in[5];
    const float* b1       = (const float*)d_in[6];
    const float* w2       = (const float*)d_in[7];
    const float* b2       = (const float*)d_in[8];
    const float* w3       = (const float*)d_in[9];
    const float* b3       = (const float*)d_in[10];
    const float* init_c2w = (const float*)d_in[11];

    // ws layout (bytes):
    // [0, 256K)           table : 4096 x 16 f32
    // [256K, +24576)      w1T   : 128 x 96 bf16
    // [.., +32768)        w2T   : 128 x 128 bf16
    char* ws = (char*)d_ws;
    float* table = (float*)ws;
    unsigned short* w1T = (unsigned short*)(ws + 262144);
    unsigned short* w2T = (unsigned short*)(ws + 262144 + 24576);

    prep_kernel<<<112, 256, 0, stream>>>(w1, w2, w1T, w2T);
    fused_kernel<<<NUM_CAMS / 16, 512, 0, stream>>>(
        t, pxy, pxz, pyz, w1T, b1, w2T, b2, w3, b3, init_c2w, table);
    gather_kernel<<<2048, 256, 0, stream>>>(
        cam_id, (const float4*)table, (float4*)d_out);
}